// Round 1
// baseline (28.141 us; speedup 1.0000x reference)
//
#include <hip/hip_runtime.h>
#include <math.h>

#define L_OBS   512
#define NSEG    8192
#define NB      8
#define EPS_PAR 1e-4f
#define ANG_STEP 0.012271846644580566f  // FOV / L_OBS

__global__ void init_ws_kernel(unsigned* __restrict__ ws) {
    int i = blockIdx.x * blockDim.x + threadIdx.x;
    if (i < NB * L_OBS) ws[i] = 0x7f800000u;  // +inf bits
}

// Block = (b, beamgroup of 64, segchunk of 512). lane = beam, wave = 128-seg subchunk.
// All 64 lanes of a wave read the SAME segment from LDS (broadcast, conflict-free).
__global__ __launch_bounds__(256) void raycast_min_kernel(
    const float4* __restrict__ seg, const float* __restrict__ pose,
    unsigned* __restrict__ ws) {
    const int SC = 16;               // seg chunks
    const int SEGS = NSEG / SC;      // 512 segs per block
    __shared__ float4 s_seg[SEGS];   // {x3, y3, sx, sy}
    __shared__ float  s_red[4][64];

    const int gid = blockIdx.x;
    const int sc = gid & (SC - 1);
    const int bg = (gid >> 4) & 7;
    const int b  = gid >> 7;

    const int tid = threadIdx.x;
    // Stage: 512 float4 by 256 threads; precompute sx,sy at stage time.
    for (int i = tid; i < SEGS; i += 256) {
        float4 v = seg[sc * SEGS + i];
        s_seg[i] = make_float4(v.x, v.y, v.z - v.x, v.w - v.y);
    }

    const float x1 = pose[b * 3 + 0];
    const float y1 = pose[b * 3 + 1];
    const float th = pose[b * 3 + 2];
    const int lane = tid & 63;
    const int w    = tid >> 6;
    const int beam = bg * 64 + lane;
    const float ang = (float)beam * ANG_STEP + th;
    const float rx = cosf(ang);
    const float ry = sinf(ang);
    __syncthreads();

    float umin = INFINITY;
    const float4* p = &s_seg[w * 128];
    #pragma unroll 4
    for (int i = 0; i < 128; ++i) {
        float4 s = p[i];
        float xd = x1 - s.x;          // x1 - x3
        float yd = y1 - s.y;          // y1 - y3
        float sx = s.z, sy = s.w;
        float rxs   = sy * rx - sx * ry;
        float num_a = sx * yd - sy * xd;
        float num_b = rx * yd - ry * xd;
        float r  = __builtin_amdgcn_rcpf(rxs);
        float ua = num_a * r;
        float ub = num_b * r;
        bool ok = (fabsf(rxs) >= EPS_PAR) & (ub >= 0.0f) & (ub <= 1.0f) & (ua >= 0.0f);
        umin = fminf(umin, ok ? ua : INFINITY);
    }

    s_red[w][lane] = umin;
    __syncthreads();
    if (w == 0) {
        float m = fminf(fminf(s_red[0][lane], s_red[1][lane]),
                        fminf(s_red[2][lane], s_red[3][lane]));
        atomicMin(&ws[b * L_OBS + beam], __float_as_uint(m));
    }
}

__global__ void finalize_kernel(const float4* __restrict__ seg,
                                const float* __restrict__ pose,
                                const unsigned* __restrict__ ws,
                                float* __restrict__ out) {
    int t = blockIdx.x * blockDim.x + threadIdx.x;
    if (t >= NB * L_OBS) return;
    const int b    = t >> 9;
    const int beam = t & (L_OBS - 1);
    const float x1 = pose[b * 3 + 0];
    const float y1 = pose[b * 3 + 1];
    const float th = pose[b * 3 + 2];
    const float ang = (float)beam * ANG_STEP + th;
    const float rx = cosf(ang), ry = sinf(ang);

    unsigned v = ws[t];
    float u;
    if (v == 0x7f800000u) {
        // No valid intersection: ref takes u_a[0] (argmin of all-inf picks idx 0).
        float4 s0 = seg[0];
        float sx = s0.z - s0.x, sy = s0.w - s0.y;
        float xd = x1 - s0.x,   yd = y1 - s0.y;
        float rxs   = sy * rx - sx * ry;
        float num_a = sx * yd - sy * xd;
        u = (fabsf(rxs) < EPS_PAR) ? 0.0f : (num_a / rxs);
    } else {
        u = __uint_as_float(v);
    }

    float ix = x1 + rx * u;
    float iy = y1 + ry * u;
    float dx = ix - x1, dy = iy - y1;
    float c = cosf(th), s = sinf(th);
    out[t * 2 + 0] = ix;
    out[t * 2 + 1] = iy;
    const int off = NB * L_OBS * 2;
    out[off + t * 2 + 0] =  dx * c + dy * s;   // R = [[c,-s],[s,c]], out = d @ R
    out[off + t * 2 + 1] = -dx * s + dy * c;
}

extern "C" void kernel_launch(void* const* d_in, const int* in_sizes, int n_in,
                              void* d_out, int out_size, void* d_ws, size_t ws_size,
                              hipStream_t stream) {
    const float4* seg  = (const float4*)d_in[0];   // (N,4) float32
    const float*  pose = (const float*)d_in[1];    // (B,3) float32
    float* out = (float*)d_out;                    // obs_global(8,512,2) ++ obs_local(8,512,2)
    unsigned* ws = (unsigned*)d_ws;                // 4096 uints = 16 KB

    init_ws_kernel<<<16, 256, 0, stream>>>(ws);
    raycast_min_kernel<<<1024, 256, 0, stream>>>(seg, pose, ws);
    finalize_kernel<<<16, 256, 0, stream>>>(seg, pose, ws, out);
}

// Round 2
// 21.463 us; speedup vs baseline: 1.3111x; 1.3111x over previous
//
#include <hip/hip_runtime.h>
#include <math.h>

#define L_OBS   512
#define NSEG    8192
#define NB      8
#define EPS_PAR 1e-4f
#define ANG_STEP 0.012271846644580566f  // FOV / L_OBS
#define SC      16
#define SEGS    (NSEG / SC)             // 512 segments per chunk

// ---------------- partial-min path (no atomics, 2 kernels) ----------------
// Block = (b, beamgroup of 64, segchunk of 512). lane = beam.
// LDS holds per-segment {sx, sy, xd, yd} and beam-independent num_a.
__global__ __launch_bounds__(256) void raycast_part_kernel(
    const float4* __restrict__ seg, const float* __restrict__ pose,
    float* __restrict__ ws) {
    __shared__ float4 s4[SEGS];     // {sx, sy, xd=x1-x3, yd=y1-y3}
    __shared__ float  sna[SEGS];    // num_a = sx*yd - sy*xd
    __shared__ float  s_red[4][64];

    const int gid = blockIdx.x;
    const int sc = gid & (SC - 1);
    const int bg = (gid >> 4) & 7;
    const int b  = gid >> 7;

    const float x1 = pose[b * 3 + 0];
    const float y1 = pose[b * 3 + 1];
    const float th = pose[b * 3 + 2];

    const int tid = threadIdx.x;
    for (int i = tid; i < SEGS; i += 256) {
        float4 v = seg[sc * SEGS + i];
        float sx = v.z - v.x, sy = v.w - v.y;
        float xd = x1 - v.x, yd = y1 - v.y;
        s4[i]  = make_float4(sx, sy, xd, yd);
        sna[i] = sx * yd - sy * xd;
    }

    const int lane = tid & 63;
    const int w    = tid >> 6;
    const int beam = bg * 64 + lane;
    const float ang = (float)beam * ANG_STEP + th;
    const float rx = cosf(ang);
    const float ry = sinf(ang);
    __syncthreads();

    float umin = INFINITY;
    const float4* p  = &s4[w * 128];
    const float*  pn = &sna[w * 128];
    #pragma unroll 8
    for (int i = 0; i < 128; ++i) {
        float4 s = p[i];           // sx, sy, xd, yd (wave-broadcast read)
        float na = pn[i];
        float rxs = s.y * rx - s.x * ry;
        float nb  = rx * s.w - ry * s.z;
        float r   = __builtin_amdgcn_rcpf(rxs);
        float ua  = na * r;
        float ub  = nb * r;
        bool ok = (fabsf(rxs) >= EPS_PAR) & (ub >= 0.0f) & (ub <= 1.0f) & (ua >= 0.0f);
        umin = fminf(umin, ok ? ua : INFINITY);
    }

    s_red[w][lane] = umin;
    __syncthreads();
    if (w == 0) {
        float m = fminf(fminf(s_red[0][lane], s_red[1][lane]),
                        fminf(s_red[2][lane], s_red[3][lane]));
        ws[sc * (NB * L_OBS) + b * L_OBS + beam] = m;
    }
}

__global__ void finalize_part_kernel(const float4* __restrict__ seg,
                                     const float* __restrict__ pose,
                                     const float* __restrict__ ws,
                                     float* __restrict__ out) {
    int t = blockIdx.x * blockDim.x + threadIdx.x;
    if (t >= NB * L_OBS) return;
    const int b    = t >> 9;
    const int beam = t & (L_OBS - 1);
    const float x1 = pose[b * 3 + 0];
    const float y1 = pose[b * 3 + 1];
    const float th = pose[b * 3 + 2];
    const float ang = (float)beam * ANG_STEP + th;
    const float rx = cosf(ang), ry = sinf(ang);

    float u = INFINITY;
    #pragma unroll
    for (int s = 0; s < SC; ++s) u = fminf(u, ws[s * (NB * L_OBS) + t]);

    if (isinf(u)) {
        // No valid intersection: ref takes u_a[0] (argmin of all-inf picks idx 0).
        float4 s0 = seg[0];
        float sx = s0.z - s0.x, sy = s0.w - s0.y;
        float xd = x1 - s0.x,   yd = y1 - s0.y;
        float rxs   = sy * rx - sx * ry;
        float num_a = sx * yd - sy * xd;
        u = (fabsf(rxs) < EPS_PAR) ? 0.0f : (num_a / rxs);
    }

    float ix = x1 + rx * u;
    float iy = y1 + ry * u;
    float dx = ix - x1, dy = iy - y1;
    float c = cosf(th), s = sinf(th);
    out[t * 2 + 0] = ix;
    out[t * 2 + 1] = iy;
    const int off = NB * L_OBS * 2;
    out[off + t * 2 + 0] =  dx * c + dy * s;   // R = [[c,-s],[s,c]], out = d @ R
    out[off + t * 2 + 1] = -dx * s + dy * c;
}

// ---------------- atomic fallback path (if ws too small) ----------------
__global__ void init_ws_kernel(unsigned* __restrict__ ws) {
    int i = blockIdx.x * blockDim.x + threadIdx.x;
    if (i < NB * L_OBS) ws[i] = 0x7f800000u;
}

__global__ __launch_bounds__(256) void raycast_atomic_kernel(
    const float4* __restrict__ seg, const float* __restrict__ pose,
    unsigned* __restrict__ ws) {
    __shared__ float4 s4[SEGS];
    __shared__ float  sna[SEGS];
    __shared__ float  s_red[4][64];
    const int gid = blockIdx.x;
    const int sc = gid & (SC - 1);
    const int bg = (gid >> 4) & 7;
    const int b  = gid >> 7;
    const float x1 = pose[b * 3 + 0];
    const float y1 = pose[b * 3 + 1];
    const float th = pose[b * 3 + 2];
    const int tid = threadIdx.x;
    for (int i = tid; i < SEGS; i += 256) {
        float4 v = seg[sc * SEGS + i];
        float sx = v.z - v.x, sy = v.w - v.y;
        float xd = x1 - v.x, yd = y1 - v.y;
        s4[i]  = make_float4(sx, sy, xd, yd);
        sna[i] = sx * yd - sy * xd;
    }
    const int lane = tid & 63;
    const int w    = tid >> 6;
    const int beam = bg * 64 + lane;
    const float ang = (float)beam * ANG_STEP + th;
    const float rx = cosf(ang), ry = sinf(ang);
    __syncthreads();
    float umin = INFINITY;
    const float4* p  = &s4[w * 128];
    const float*  pn = &sna[w * 128];
    #pragma unroll 8
    for (int i = 0; i < 128; ++i) {
        float4 s = p[i];
        float na = pn[i];
        float rxs = s.y * rx - s.x * ry;
        float nb  = rx * s.w - ry * s.z;
        float r   = __builtin_amdgcn_rcpf(rxs);
        float ua  = na * r;
        float ub  = nb * r;
        bool ok = (fabsf(rxs) >= EPS_PAR) & (ub >= 0.0f) & (ub <= 1.0f) & (ua >= 0.0f);
        umin = fminf(umin, ok ? ua : INFINITY);
    }
    s_red[w][lane] = umin;
    __syncthreads();
    if (w == 0) {
        float m = fminf(fminf(s_red[0][lane], s_red[1][lane]),
                        fminf(s_red[2][lane], s_red[3][lane]));
        atomicMin(&ws[b * L_OBS + beam], __float_as_uint(m));
    }
}

__global__ void finalize_atomic_kernel(const float4* __restrict__ seg,
                                       const float* __restrict__ pose,
                                       const unsigned* __restrict__ ws,
                                       float* __restrict__ out) {
    int t = blockIdx.x * blockDim.x + threadIdx.x;
    if (t >= NB * L_OBS) return;
    const int b    = t >> 9;
    const int beam = t & (L_OBS - 1);
    const float x1 = pose[b * 3 + 0];
    const float y1 = pose[b * 3 + 1];
    const float th = pose[b * 3 + 2];
    const float ang = (float)beam * ANG_STEP + th;
    const float rx = cosf(ang), ry = sinf(ang);
    unsigned v = ws[t];
    float u;
    if (v == 0x7f800000u) {
        float4 s0 = seg[0];
        float sx = s0.z - s0.x, sy = s0.w - s0.y;
        float xd = x1 - s0.x,   yd = y1 - s0.y;
        float rxs   = sy * rx - sx * ry;
        float num_a = sx * yd - sy * xd;
        u = (fabsf(rxs) < EPS_PAR) ? 0.0f : (num_a / rxs);
    } else {
        u = __uint_as_float(v);
    }
    float ix = x1 + rx * u;
    float iy = y1 + ry * u;
    float dx = ix - x1, dy = iy - y1;
    float c = cosf(th), s = sinf(th);
    out[t * 2 + 0] = ix;
    out[t * 2 + 1] = iy;
    const int off = NB * L_OBS * 2;
    out[off + t * 2 + 0] =  dx * c + dy * s;
    out[off + t * 2 + 1] = -dx * s + dy * c;
}

extern "C" void kernel_launch(void* const* d_in, const int* in_sizes, int n_in,
                              void* d_out, int out_size, void* d_ws, size_t ws_size,
                              hipStream_t stream) {
    const float4* seg  = (const float4*)d_in[0];   // (N,4) float32
    const float*  pose = (const float*)d_in[1];    // (B,3) float32
    float* out = (float*)d_out;

    if (ws_size >= (size_t)SC * NB * L_OBS * sizeof(float)) {
        float* ws = (float*)d_ws;                  // [SC][NB*L_OBS] partial mins
        raycast_part_kernel<<<1024, 256, 0, stream>>>(seg, pose, ws);
        finalize_part_kernel<<<16, 256, 0, stream>>>(seg, pose, ws, out);
    } else {
        unsigned* ws = (unsigned*)d_ws;
        init_ws_kernel<<<16, 256, 0, stream>>>(ws);
        raycast_atomic_kernel<<<1024, 256, 0, stream>>>(seg, pose, ws);
        finalize_atomic_kernel<<<16, 256, 0, stream>>>(seg, pose, ws, out);
    }
}